// Round 1
// baseline (1260.167 us; speedup 1.0000x reference)
//
#include <hip/hip_runtime.h>
#include <hip/hip_bf16.h>

#define SL 2048      // sequence length
#define NK 24        // num filters
#define NI 256       // input dim
#define NO 256       // output dim
#define NB 2         // batch
#define NC 48        // 2*NK channels (plus/minus folded into filters)
#define TD 64        // tile dim
#define NT 32        // l-tiles per batch (SL/TD)

typedef __bf16 bf16x8 __attribute__((ext_vector_type(8)));
typedef float f32x4 __attribute__((ext_vector_type(4)));

// workspace layout (bytes)
#define OFF_T   0ull                      // Toeplitz bank [32][48][64][64] bf16
#define SZ_T    (32ull*48*64*64*2)        // 12,582,912
#define OFF_MT  (OFF_T + SZ_T)            // M_T [48][256][256] bf16 ([c][o][i])
#define SZ_MT   (48ull*256*256*2)         // 6,291,456
#define OFF_XB  (OFF_MT + SZ_MT)          // x bf16 [2][2048][256]
#define SZ_XB   (2ull*2048*256*2)         // 2,097,152
#define OFF_YT  (OFF_XB + SZ_XB)          // Y_T [2][48][256][2048] bf16 ([b][c][o][t])
#define SZ_YT   (2ull*48*256*2048*2)      // 100,663,296
#define WS_NEED (OFF_YT + SZ_YT)          // ~121.6 MB

__device__ __forceinline__ unsigned short f2bf(float f) {
    unsigned int u = __float_as_uint(f);
    unsigned int r = (u + 0x7FFFu + ((u >> 16) & 1u)) >> 16;
    return (unsigned short)r;
}

// ---- kernel 0a: x f32 -> bf16 -------------------------------------------
__global__ void k_cvt_x(const float* __restrict__ x, unsigned short* __restrict__ xb) {
    int i = blockIdx.x * blockDim.x + threadIdx.x;   // float4 index, 262144 total
    float4 v = reinterpret_cast<const float4*>(x)[i];
    ushort4 o;
    o.x = f2bf(v.x); o.y = f2bf(v.y); o.z = f2bf(v.z); o.w = f2bf(v.w);
    reinterpret_cast<ushort4*>(xb)[i] = o;
}

// ---- kernel 0b: M [k][i][o] f32 -> M_T [c][o][i] bf16 -------------------
__global__ void k_mt(const float* __restrict__ Mp, const float* __restrict__ Mm,
                     unsigned short* __restrict__ mt) {
    __shared__ float tile[64][65];
    int c = blockIdx.x, it = blockIdx.y, ot = blockIdx.z;
    int k = c >> 1;
    const float* M = (c & 1) ? Mm : Mp;
    int tid = threadIdx.x;
    int col = tid & 63, rq = tid >> 6;          // 4 rows per pass
    for (int rr = 0; rr < 64; rr += 4) {
        int i = rr + rq;
        tile[i][col] = M[((k * NI) + (it * 64 + i)) * NO + ot * 64 + col];
    }
    __syncthreads();
    for (int rr = 0; rr < 64; rr += 4) {
        int o = rr + rq;
        mt[((c * NO) + (ot * 64 + o)) * NI + it * 64 + col] = f2bf(tile[col][o]);
    }
}

// ---- kernel 1: Toeplitz bank T[d][c][li][ti] = F[64d+li-ti, c] ----------
__global__ void k_toep(const float* __restrict__ phi, unsigned short* __restrict__ T) {
    int d = blockIdx.x, c = blockIdx.y;
    int ti = threadIdx.x;                        // 64 threads
    int k = c >> 1, odd = c & 1;
    for (int li = 0; li < TD; ++li) {
        int s = d * TD + li - ti;
        float v = 0.f;
        if (s >= 0 && s < SL) {
            v = phi[s * NK + k];
            if (odd && (s & 1)) v = -v;
        }
        T[((d * NC + c) * TD + li) * TD + ti] = f2bf(v);
    }
}

// ---- kernel 2: Y_T[b][c][o][t] = sum_i x[b,t,i] * M_c[i,o] --------------
__global__ __launch_bounds__(256) void k_gemm1(const unsigned short* __restrict__ xb,
                                               const unsigned short* __restrict__ mt,
                                               unsigned short* __restrict__ yt) {
    int rb = blockIdx.x;          // 64 row-blocks of 64 over B*L=4096
    int c  = blockIdx.y;          // 48
    int ob = blockIdx.z;          // 4 col-blocks of 64
    int tid = threadIdx.x;
    int lane = tid & 63, wid = tid >> 6;
    int wr = wid >> 1, wc = wid & 1;
    int r0 = rb * 64, o0 = ob * 64;
    int ln15 = lane & 15, lq = lane >> 4;

    f32x4 acc[2][2];
    f32x4 z = {0.f, 0.f, 0.f, 0.f};
    for (int mi = 0; mi < 2; ++mi) for (int ni = 0; ni < 2; ++ni) acc[mi][ni] = z;

    for (int i0 = 0; i0 < NI; i0 += 32) {
        bf16x8 a[2], b[2];
        for (int mi = 0; mi < 2; ++mi)
            a[mi] = *reinterpret_cast<const bf16x8*>(
                xb + (r0 + wr * 32 + mi * 16 + ln15) * NI + i0 + lq * 8);
        for (int ni = 0; ni < 2; ++ni)
            b[ni] = *reinterpret_cast<const bf16x8*>(
                mt + (c * NO + o0 + wc * 32 + ni * 16 + ln15) * NI + i0 + lq * 8);
        for (int mi = 0; mi < 2; ++mi)
            for (int ni = 0; ni < 2; ++ni)
                acc[mi][ni] = __builtin_amdgcn_mfma_f32_16x16x32_bf16(a[mi], b[ni], acc[mi][ni], 0, 0, 0);
    }

    int b_ = r0 >> 11, t0 = r0 & (SL - 1);
    for (int mi = 0; mi < 2; ++mi)
        for (int ni = 0; ni < 2; ++ni) {
            int t = t0 + wr * 32 + mi * 16 + lq * 4;
            int o = o0 + wc * 32 + ni * 16 + ln15;
            ushort4 pk;
            pk.x = f2bf(acc[mi][ni][0]);
            pk.y = f2bf(acc[mi][ni][1]);
            pk.z = f2bf(acc[mi][ni][2]);
            pk.w = f2bf(acc[mi][ni][3]);
            *reinterpret_cast<ushort4*>(yt + (((size_t)b_ * NC + c) * NO + o) * SL + t) = pk;
        }
}

// ---- kernel 3: out[b,l,o] = sum_{tt<=lt} sum_c T[d,c] . Y[b,tt,c,:] -----
__global__ __launch_bounds__(256) void k_conv(const unsigned short* __restrict__ T,
                                              const unsigned short* __restrict__ yt,
                                              float* __restrict__ out) {
    int ob = blockIdx.x;          // 8 col-blocks of 32
    int p  = blockIdx.y;          // 16 balanced pairs
    int b_ = blockIdx.z;          // 2
    int tid = threadIdx.x, lane = tid & 63, wid = tid >> 6;
    int ln15 = lane & 15, lq = lane >> 4;
    int o0 = ob * 32;
    f32x4 z = {0.f, 0.f, 0.f, 0.f};

    for (int half = 0; half < 2; ++half) {
        int lt = half ? (31 - p) : p;
        // acc[parity][ni] : parity over c breaks the MFMA dependency chain
        f32x4 acc[2][2];
        acc[0][0] = z; acc[0][1] = z; acc[1][0] = z; acc[1][1] = z;

        for (int tt = 0; tt <= lt; ++tt) {
            int d = lt - tt;
            const unsigned short* Tb = T + (size_t)(d * NC) * TD * TD;
            const unsigned short* Yb = yt + ((size_t)b_ * NC * NO) * SL;
            for (int c = 0; c < NC; ++c) {
#pragma unroll
                for (int kk = 0; kk < 2; ++kk) {
                    bf16x8 a = *reinterpret_cast<const bf16x8*>(
                        Tb + ((size_t)c * TD + wid * 16 + ln15) * TD + kk * 32 + lq * 8);
#pragma unroll
                    for (int ni = 0; ni < 2; ++ni) {
                        bf16x8 bv = *reinterpret_cast<const bf16x8*>(
                            Yb + ((size_t)c * NO + o0 + ni * 16 + ln15) * SL + tt * 64 + kk * 32 + lq * 8);
                        acc[c & 1][ni] = __builtin_amdgcn_mfma_f32_16x16x32_bf16(a, bv, acc[c & 1][ni], 0, 0, 0);
                    }
                }
            }
        }

        int l0 = lt * 64;
#pragma unroll
        for (int ni = 0; ni < 2; ++ni) {
            f32x4 s = acc[0][ni] + acc[1][ni];
#pragma unroll
            for (int r = 0; r < 4; ++r) {
                int l = l0 + wid * 16 + lq * 4 + r;
                int o = o0 + ni * 16 + ln15;
                out[((size_t)b_ * SL + l) * NO + o] = s[r];
            }
        }
    }
}

extern "C" void kernel_launch(void* const* d_in, const int* in_sizes, int n_in,
                              void* d_out, int out_size, void* d_ws, size_t ws_size,
                              hipStream_t stream) {
    const float* x   = (const float*)d_in[0];
    const float* phi = (const float*)d_in[1];
    const float* Mp  = (const float*)d_in[2];
    const float* Mm  = (const float*)d_in[3];
    float* out = (float*)d_out;

    if (ws_size < WS_NEED) return;  // diagnostic: leaves out zeroed -> absmax == max|ref|

    char* ws = (char*)d_ws;
    unsigned short* T  = (unsigned short*)(ws + OFF_T);
    unsigned short* MT = (unsigned short*)(ws + OFF_MT);
    unsigned short* XB = (unsigned short*)(ws + OFF_XB);
    unsigned short* YT = (unsigned short*)(ws + OFF_YT);

    k_cvt_x<<<dim3(262144 / 256), dim3(256), 0, stream>>>(x, XB);
    k_mt<<<dim3(48, 4, 4), dim3(256), 0, stream>>>(Mp, Mm, MT);
    k_toep<<<dim3(32, 48), dim3(64), 0, stream>>>(phi, T);
    k_gemm1<<<dim3(64, 48, 4), dim3(256), 0, stream>>>(XB, MT, YT);
    k_conv<<<dim3(8, 16, 2), dim3(256), 0, stream>>>(T, YT, out);
}

// Round 2
// 285.539 us; speedup vs baseline: 4.4133x; 4.4133x over previous
//
#include <hip/hip_runtime.h>
#include <hip/hip_bf16.h>

#define SL 2048
#define NK 24
#define NI 256
#define NO 256
#define NB 2
#define NC 48
#define TD 64

typedef __bf16 bf16x8 __attribute__((ext_vector_type(8)));
typedef float f32x4 __attribute__((ext_vector_type(4)));
typedef unsigned short u16x8 __attribute__((ext_vector_type(8)));
typedef unsigned short ushort_t;
typedef unsigned int u32;

// workspace layout (bytes)
#define OFF_T   0ull                      // Toeplitz bank [33][48][64][64] bf16 (slot 0 = zeros, slot d+1 = diag d)
#define SZ_T    (33ull*48*64*64*2)        // 12,976,128
#define OFF_MT  (OFF_T + SZ_T)            // M_T [48][256][256] bf16 ([c][o][i])
#define SZ_MT   (48ull*256*256*2)
#define OFF_XB  (OFF_MT + SZ_MT)          // x bf16 [2][2048][256]
#define SZ_XB   (2ull*2048*256*2)
#define OFF_YT  (OFF_XB + SZ_XB)          // Y_T [2][48][256][2048] bf16 ([b][c][o][t])
#define SZ_YT   (2ull*48*256*2048*2)
#define WS_NEED (OFF_YT + SZ_YT)          // ~122.0 MB

__device__ __forceinline__ unsigned short f2bf(float f) {
    unsigned int u = __float_as_uint(f);
    unsigned int r = (u + 0x7FFFu + ((u >> 16) & 1u)) >> 16;
    return (unsigned short)r;
}

__device__ __forceinline__ void glds16(ushort_t* l, const ushort_t* g) {
    __builtin_amdgcn_global_load_lds((const __attribute__((address_space(1))) u32*)g,
                                     (__attribute__((address_space(3))) u32*)l, 16, 0, 0);
}

// ---- kernel 0a: x f32 -> bf16 -------------------------------------------
__global__ void k_cvt_x(const float* __restrict__ x, ushort_t* __restrict__ xb) {
    int i = blockIdx.x * blockDim.x + threadIdx.x;
    float4 v = reinterpret_cast<const float4*>(x)[i];
    ushort4 o;
    o.x = f2bf(v.x); o.y = f2bf(v.y); o.z = f2bf(v.z); o.w = f2bf(v.w);
    reinterpret_cast<ushort4*>(xb)[i] = o;
}

// ---- kernel 0b: M [k][i][o] f32 -> M_T [c][o][i] bf16 -------------------
__global__ void k_mt(const float* __restrict__ Mp, const float* __restrict__ Mm,
                     ushort_t* __restrict__ mt) {
    __shared__ float tile[64][65];
    int c = blockIdx.x, it = blockIdx.y, ot = blockIdx.z;
    int k = c >> 1;
    const float* M = (c & 1) ? Mm : Mp;
    int tid = threadIdx.x;
    int col = tid & 63, rq = tid >> 6;
    for (int rr = 0; rr < 64; rr += 4) {
        int i = rr + rq;
        tile[i][col] = M[((k * NI) + (it * 64 + i)) * NO + ot * 64 + col];
    }
    __syncthreads();
    for (int rr = 0; rr < 64; rr += 4) {
        int o = rr + rq;
        mt[((c * NO) + (ot * 64 + o)) * NI + it * 64 + col] = f2bf(tile[col][o]);
    }
}

// ---- kernel 1: Toeplitz bank, slot s=d+1: Tb2[s][c][li][ti] = F[64d+li-ti, c]
__global__ void k_toep(const float* __restrict__ phi, ushort_t* __restrict__ T) {
    int d = (int)blockIdx.x - 1, c = blockIdx.y;
    int ti = threadIdx.x;
    int k = c >> 1, odd = c & 1;
    for (int li = 0; li < TD; ++li) {
        int s = d * TD + li - ti;
        float v = 0.f;
        if (s >= 0 && s < SL) {
            v = phi[s * NK + k];
            if (odd && (s & 1)) v = -v;
        }
        T[(((blockIdx.x) * NC + c) * TD + li) * TD + ti] = f2bf(v);
    }
}

// ---- kernel 2: Y_T[b][c][o][t] = sum_i x[b,t,i] * M_c[i,o] --------------
// GEMM: A = XB [4096 rows=(b,t)][256], B = MT [12288 rows=(c,o)][256]
// 128x128 tile, BK=32, 4 waves x (64x64), glds staging, dbuf.
__global__ __launch_bounds__(256, 2) void k_gemm1(const ushort_t* __restrict__ XB,
                                                  const ushort_t* __restrict__ MT,
                                                  ushort_t* __restrict__ yt) {
    __shared__ ushort_t sh[2 * 8192];
    int nb_ = blockIdx.x;          // 96 col-blocks
    int rb  = blockIdx.y;          // 32 row-blocks
    int n0 = nb_ * 128;
    int tid = threadIdx.x, lane = tid & 63, wid = tid >> 6;
    int wr = wid >> 1, wc = wid & 1;
    int ln15 = lane & 15, lq = lane >> 4;

    const ushort_t* Arow = XB + (size_t)(rb * 128) * 256;
    const ushort_t* Brow = MT + (size_t)n0 * 256;

    auto stage = [&](int bufsel, int s) {
        ushort_t* L = sh + bufsel * 8192;
        int k0 = s * 32;
#pragma unroll
        for (int jj = 0; jj < 2; ++jj) {
            int flat = tid + jj * 256;
            int row = flat >> 2, k8 = flat & 3;
            glds16(L + flat * 8, Arow + row * 256 + k0 + k8 * 8);
        }
#pragma unroll
        for (int jj = 0; jj < 2; ++jj) {
            int flat = tid + jj * 256;
            int row = flat >> 2, k8 = flat & 3;
            glds16(L + 4096 + flat * 8, Brow + row * 256 + k0 + k8 * 8);
        }
    };

    f32x4 acc[4][4];
    f32x4 z = {0.f, 0.f, 0.f, 0.f};
#pragma unroll
    for (int mi = 0; mi < 4; ++mi)
#pragma unroll
        for (int ni = 0; ni < 4; ++ni) acc[mi][ni] = z;

    stage(0, 0);
    __syncthreads();
    for (int s = 0; s < 8; ++s) {
        int cur = s & 1;
        if (s < 7) stage(cur ^ 1, s + 1);
        const ushort_t* Ab = sh + cur * 8192;
        const ushort_t* Bb = Ab + 4096;
        bf16x8 af[4], bfr[4];
#pragma unroll
        for (int mi = 0; mi < 4; ++mi)
            af[mi] = *reinterpret_cast<const bf16x8*>(Ab + (wr * 64 + mi * 16 + ln15) * 32 + lq * 8);
#pragma unroll
        for (int ni = 0; ni < 4; ++ni)
            bfr[ni] = *reinterpret_cast<const bf16x8*>(Bb + (wc * 64 + ni * 16 + ln15) * 32 + lq * 8);
#pragma unroll
        for (int mi = 0; mi < 4; ++mi)
#pragma unroll
            for (int ni = 0; ni < 4; ++ni)
                acc[mi][ni] = __builtin_amdgcn_mfma_f32_16x16x32_bf16(af[mi], bfr[ni], acc[mi][ni], 0, 0, 0);
        __syncthreads();
    }

    // epilogue: transpose through LDS -> coalesced [row=(c,o)][t] writes
    ushort_t* OT = sh;  // [128 n][128 t] bf16 = 32KB
#pragma unroll
    for (int mi = 0; mi < 4; ++mi)
#pragma unroll
        for (int ni = 0; ni < 4; ++ni) {
            int t_loc = wr * 64 + mi * 16 + lq * 4;
            int n_loc = wc * 64 + ni * 16 + ln15;
            ushort4 pk;
            pk.x = f2bf(acc[mi][ni][0]);
            pk.y = f2bf(acc[mi][ni][1]);
            pk.z = f2bf(acc[mi][ni][2]);
            pk.w = f2bf(acc[mi][ni][3]);
            *reinterpret_cast<ushort4*>(OT + n_loc * 128 + t_loc) = pk;
        }
    __syncthreads();
    int b = rb >> 4, t0 = (rb & 15) * 128;
#pragma unroll
    for (int jj = 0; jj < 8; ++jj) {
        int flat = tid + jj * 256;           // 2048 chunks of 16B
        int n_loc = flat >> 4, te = (flat & 15) * 8;
        int nn = n0 + n_loc;
        int c = nn >> 8, o = nn & 255;
        *reinterpret_cast<u16x8*>(yt + ((size_t)(b * NC + c) * NO + o) * SL + t0 + te) =
            *reinterpret_cast<const u16x8*>(OT + n_loc * 128 + te);
    }
}

// ---- kernel 3: conv as split-K block-Toeplitz GEMM ----------------------
// groups g=(b,ob,p): out tile rows l=[128p,128p+128), cols o=[128ob,+128), batch b
// K-stream per group: half-units h=0..4p+3 (tt=h>>1, kk-half=h&1), 48 c-steps each.
// nb[p] blocks per group, acc flushed via atomicAdd (direct store if nb==1).
__global__ __launch_bounds__(256, 2) void k_conv(const ushort_t* __restrict__ Tb2,
                                                 const ushort_t* __restrict__ yt,
                                                 float* __restrict__ out) {
    __shared__ ushort_t sh[2 * 8192];
    const int NBt[16] = {1, 2, 3, 4, 5, 6, 7, 8, 8, 9, 10, 11, 12, 13, 14, 15};

    int blk = blockIdx.x;                        // 512
    int orig = (blk & 7) * 64 + (blk >> 3);      // XCD-contiguous remap (bijective)
    int bo = orig >> 7;
    int b_ = bo >> 1, ob = bo & 1;
    int j = orig & 127;
    int p = 0, base = 0;
    while (p < 15 && j >= base + NBt[p]) { base += NBt[p]; ++p; }
    int idx = j - base, n = NBt[p];
    int H = 4 * (p + 1);
    int u0 = idx * H / n, u1 = (idx + 1) * H / n;
    int nsteps = (u1 - u0) * 48;

    int tid = threadIdx.x, lane = tid & 63, wid = tid >> 6;
    int wr = wid >> 1, wc = wid & 1;
    int ln15 = lane & 15, lq = lane >> 4;

    auto stage = [&](int bufsel, int h, int c) {
        int tt = h >> 1, kk = h & 1;
        int d0 = 2 * p - tt;
        const ushort_t* Asrc = Tb2 + ((size_t)((d0 + 1) * NC + c) << 12) + kk * 32;
        const ushort_t* Bsrc = yt + ((size_t)((b_ * NC + c) * NO + ob * 128) << 11) + tt * 64 + kk * 32;
        ushort_t* L = sh + bufsel * 8192;
#pragma unroll
        for (int jj = 0; jj < 2; ++jj) {
            int flat = tid + jj * 256;
            int row = flat >> 2, k8 = flat & 3;
            glds16(L + flat * 8, Asrc + ((row >> 6) * NC << 12) + (row & 63) * 64 + k8 * 8);
        }
#pragma unroll
        for (int jj = 0; jj < 2; ++jj) {
            int flat = tid + jj * 256;
            int row = flat >> 2, k8 = flat & 3;
            glds16(L + 4096 + flat * 8, Bsrc + row * 2048 + k8 * 8);
        }
    };

    f32x4 acc[4][4];
    f32x4 z = {0.f, 0.f, 0.f, 0.f};
#pragma unroll
    for (int mi = 0; mi < 4; ++mi)
#pragma unroll
        for (int ni = 0; ni < 4; ++ni) acc[mi][ni] = z;

    int h = u0, c = 0;
    stage(0, h, c);
    int hn = h, cn = 1;
    if (cn == 48) { cn = 0; hn++; }
    __syncthreads();

    for (int s = 0; s < nsteps; ++s) {
        int cur = s & 1;
        if (s + 1 < nsteps) {
            stage(cur ^ 1, hn, cn);
            if (++cn == 48) { cn = 0; ++hn; }
        }
        const ushort_t* Ab = sh + cur * 8192;
        const ushort_t* Bb = Ab + 4096;
        bf16x8 af[4], bfr[4];
#pragma unroll
        for (int mi = 0; mi < 4; ++mi)
            af[mi] = *reinterpret_cast<const bf16x8*>(Ab + (wr * 64 + mi * 16 + ln15) * 32 + lq * 8);
#pragma unroll
        for (int ni = 0; ni < 4; ++ni)
            bfr[ni] = *reinterpret_cast<const bf16x8*>(Bb + (wc * 64 + ni * 16 + ln15) * 32 + lq * 8);
#pragma unroll
        for (int mi = 0; mi < 4; ++mi)
#pragma unroll
            for (int ni = 0; ni < 4; ++ni)
                acc[mi][ni] = __builtin_amdgcn_mfma_f32_16x16x32_bf16(af[mi], bfr[ni], acc[mi][ni], 0, 0, 0);
        __syncthreads();
    }

    float* outp = out + ((size_t)b_ * SL + p * 128) * NO + ob * 128;
#pragma unroll
    for (int mi = 0; mi < 4; ++mi)
#pragma unroll
        for (int ni = 0; ni < 4; ++ni) {
            int l = wr * 64 + mi * 16 + lq * 4;
            int o = wc * 64 + ni * 16 + ln15;
#pragma unroll
            for (int r = 0; r < 4; ++r) {
                float v = acc[mi][ni][r];
                if (n == 1) outp[(l + r) * NO + o] = v;
                else atomicAdd(&outp[(l + r) * NO + o], v);
            }
        }
}

extern "C" void kernel_launch(void* const* d_in, const int* in_sizes, int n_in,
                              void* d_out, int out_size, void* d_ws, size_t ws_size,
                              hipStream_t stream) {
    const float* x   = (const float*)d_in[0];
    const float* phi = (const float*)d_in[1];
    const float* Mp  = (const float*)d_in[2];
    const float* Mm  = (const float*)d_in[3];
    float* out = (float*)d_out;

    if (ws_size < WS_NEED) return;

    char* ws = (char*)d_ws;
    ushort_t* T  = (ushort_t*)(ws + OFF_T);
    ushort_t* MT = (ushort_t*)(ws + OFF_MT);
    ushort_t* XB = (ushort_t*)(ws + OFF_XB);
    ushort_t* YT = (ushort_t*)(ws + OFF_YT);

    hipMemsetAsync(d_out, 0, (size_t)out_size * sizeof(float), stream);
    k_cvt_x<<<dim3(262144 / 256), dim3(256), 0, stream>>>(x, XB);
    k_mt<<<dim3(48, 4, 4), dim3(256), 0, stream>>>(Mp, Mm, MT);
    k_toep<<<dim3(33, 48), dim3(64), 0, stream>>>(phi, T);
    k_gemm1<<<dim3(96, 32), dim3(256), 0, stream>>>(XB, MT, YT);
    k_conv<<<dim3(512), dim3(256), 0, stream>>>(T, YT, out);
}

// Round 3
// 243.940 us; speedup vs baseline: 5.1659x; 1.1705x over previous
//
#include <hip/hip_runtime.h>
#include <hip/hip_bf16.h>

#define SL 2048
#define NK 24
#define NI 256
#define NO 256
#define NB 2
#define NC 48
#define TD 64

typedef __bf16 bf16x8 __attribute__((ext_vector_type(8)));
typedef float f32x4 __attribute__((ext_vector_type(4)));
typedef unsigned short u16x8 __attribute__((ext_vector_type(8)));
typedef unsigned short ushort_t;
typedef unsigned int u32;

// workspace layout (bytes)
#define OFF_T   0ull                      // Toeplitz bank [33][48][64][64] bf16 (slot 0 = zeros, slot d+1 = diag d)
#define SZ_T    (33ull*48*64*64*2)
#define OFF_MT  (OFF_T + SZ_T)            // M_T [48][256][256] bf16 ([c][o][i])
#define SZ_MT   (48ull*256*256*2)
#define OFF_XB  (OFF_MT + SZ_MT)          // x bf16 [2][2048][256]
#define SZ_XB   (2ull*2048*256*2)
#define OFF_YT  (OFF_XB + SZ_XB)          // Y_T [2][48][256][2048] bf16 ([b][c][o][t])
#define SZ_YT   (2ull*48*256*2048*2)
#define WS_NEED (OFF_YT + SZ_YT)

__device__ __forceinline__ unsigned short f2bf(float f) {
    unsigned int u = __float_as_uint(f);
    unsigned int r = (u + 0x7FFFu + ((u >> 16) & 1u)) >> 16;
    return (unsigned short)r;
}

__device__ __forceinline__ void glds16(ushort_t* l, const ushort_t* g) {
    __builtin_amdgcn_global_load_lds((const __attribute__((address_space(1))) u32*)g,
                                     (__attribute__((address_space(3))) u32*)l, 16, 0, 0);
}

// ---- kernel 0a: x f32 -> bf16 -------------------------------------------
__global__ void k_cvt_x(const float* __restrict__ x, ushort_t* __restrict__ xb) {
    int i = blockIdx.x * blockDim.x + threadIdx.x;
    float4 v = reinterpret_cast<const float4*>(x)[i];
    ushort4 o;
    o.x = f2bf(v.x); o.y = f2bf(v.y); o.z = f2bf(v.z); o.w = f2bf(v.w);
    reinterpret_cast<ushort4*>(xb)[i] = o;
}

// ---- kernel 0b: M [k][i][o] f32 -> M_T [c][o][i] bf16 -------------------
__global__ void k_mt(const float* __restrict__ Mp, const float* __restrict__ Mm,
                     ushort_t* __restrict__ mt) {
    __shared__ float tile[64][65];
    int c = blockIdx.x, it = blockIdx.y, ot = blockIdx.z;
    int k = c >> 1;
    const float* M = (c & 1) ? Mm : Mp;
    int tid = threadIdx.x;
    int col = tid & 63, rq = tid >> 6;
    for (int rr = 0; rr < 64; rr += 4) {
        int i = rr + rq;
        tile[i][col] = M[((k * NI) + (it * 64 + i)) * NO + ot * 64 + col];
    }
    __syncthreads();
    for (int rr = 0; rr < 64; rr += 4) {
        int o = rr + rq;
        mt[((c * NO) + (ot * 64 + o)) * NI + it * 64 + col] = f2bf(tile[col][o]);
    }
}

// ---- kernel 1: Toeplitz bank, slot s=d+1: Tb2[s][c][li][ti] = F[64d+li-ti, c]
__global__ void k_toep(const float* __restrict__ phi, ushort_t* __restrict__ T) {
    int d = (int)blockIdx.x - 1, c = blockIdx.y;
    int ti = threadIdx.x;
    int k = c >> 1, odd = c & 1;
    for (int li = 0; li < TD; ++li) {
        int s = d * TD + li - ti;
        float v = 0.f;
        if (s >= 0 && s < SL) {
            v = phi[s * NK + k];
            if (odd && (s & 1)) v = -v;
        }
        T[(((blockIdx.x) * NC + c) * TD + li) * TD + ti] = f2bf(v);
    }
}

// ---- kernel 2: Y_T[b][c][o][t] = sum_i x[b,t,i] * M_c[i,o] --------------
// 128x128 tile, BK=32, 4 waves x (64x64), glds staging (pre-swizzled source),
// swizzled ds_read (slot ^= (row>>1)&3 -> 2-way bank aliasing = free).
__global__ __launch_bounds__(256, 3) void k_gemm1(const ushort_t* __restrict__ XB,
                                                  const ushort_t* __restrict__ MT,
                                                  ushort_t* __restrict__ yt) {
    __shared__ ushort_t sh[17408];   // stage: 2x8192; epilogue OT: 128x136
    int nb_ = blockIdx.x;          // 96 col-blocks
    int rb  = blockIdx.y;          // 32 row-blocks
    int n0 = nb_ * 128;
    int tid = threadIdx.x, lane = tid & 63, wid = tid >> 6;
    int wr = wid >> 1, wc = wid & 1;
    int ln15 = lane & 15, lq = lane >> 4;
    int swz = lq ^ ((ln15 >> 1) & 3);        // read-side swizzled 16B slot

    const ushort_t* Arow = XB + (size_t)(rb * 128) * 256;
    const ushort_t* Brow = MT + (size_t)n0 * 256;

    auto stage = [&](int bufsel, int s) {
        ushort_t* L = sh + bufsel * 8192;
        int k0 = s * 32;
#pragma unroll
        for (int jj = 0; jj < 2; ++jj) {
            int flat = tid + jj * 256;
            int row = flat >> 2;
            int k8s = (flat & 3) ^ ((flat >> 3) & 3);   // pre-swizzled source chunk
            glds16(L + flat * 8, Arow + row * 256 + k0 + k8s * 8);
        }
#pragma unroll
        for (int jj = 0; jj < 2; ++jj) {
            int flat = tid + jj * 256;
            int row = flat >> 2;
            int k8s = (flat & 3) ^ ((flat >> 3) & 3);
            glds16(L + 4096 + flat * 8, Brow + row * 256 + k0 + k8s * 8);
        }
    };

    f32x4 acc[4][4];
    f32x4 z = {0.f, 0.f, 0.f, 0.f};
#pragma unroll
    for (int mi = 0; mi < 4; ++mi)
#pragma unroll
        for (int ni = 0; ni < 4; ++ni) acc[mi][ni] = z;

    stage(0, 0);
    __syncthreads();
    for (int s = 0; s < 8; ++s) {
        int cur = s & 1;
        if (s < 7) stage(cur ^ 1, s + 1);
        const ushort_t* Ab = sh + cur * 8192;
        const ushort_t* Bb = Ab + 4096;
        bf16x8 af[4], bfr[4];
#pragma unroll
        for (int mi = 0; mi < 4; ++mi)
            af[mi] = *reinterpret_cast<const bf16x8*>(Ab + (wr * 64 + mi * 16 + ln15) * 32 + swz * 8);
#pragma unroll
        for (int ni = 0; ni < 4; ++ni)
            bfr[ni] = *reinterpret_cast<const bf16x8*>(Bb + (wc * 64 + ni * 16 + ln15) * 32 + swz * 8);
#pragma unroll
        for (int mi = 0; mi < 4; ++mi)
#pragma unroll
            for (int ni = 0; ni < 4; ++ni)
                acc[mi][ni] = __builtin_amdgcn_mfma_f32_16x16x32_bf16(af[mi], bfr[ni], acc[mi][ni], 0, 0, 0);
        __syncthreads();
    }

    // epilogue: transpose through LDS (stride 136 kills the 16-way write conflict)
    ushort_t* OT = sh;  // [128 n][136] bf16
#pragma unroll
    for (int mi = 0; mi < 4; ++mi)
#pragma unroll
        for (int ni = 0; ni < 4; ++ni) {
            int t_loc = wr * 64 + mi * 16 + lq * 4;
            int n_loc = wc * 64 + ni * 16 + ln15;
            ushort4 pk;
            pk.x = f2bf(acc[mi][ni][0]);
            pk.y = f2bf(acc[mi][ni][1]);
            pk.z = f2bf(acc[mi][ni][2]);
            pk.w = f2bf(acc[mi][ni][3]);
            *reinterpret_cast<ushort4*>(OT + n_loc * 136 + t_loc) = pk;
        }
    __syncthreads();
    int b = rb >> 4, t0 = (rb & 15) * 128;
#pragma unroll
    for (int jj = 0; jj < 8; ++jj) {
        int flat = tid + jj * 256;           // 2048 chunks of 16B
        int n_loc = flat >> 4, te = (flat & 15) * 8;
        int nn = n0 + n_loc;
        int c = nn >> 8, o = nn & 255;
        *reinterpret_cast<u16x8*>(yt + ((size_t)(b * NC + c) * NO + o) * SL + t0 + te) =
            *reinterpret_cast<const u16x8*>(OT + n_loc * 136 + te);
    }
}

// ---- kernel 3: conv as split-K block-Toeplitz GEMM ----------------------
__global__ __launch_bounds__(256, 3) void k_conv(const ushort_t* __restrict__ Tb2,
                                                 const ushort_t* __restrict__ yt,
                                                 float* __restrict__ out) {
    __shared__ ushort_t sh[2 * 8192];
    // blocks per group, proportional to K-length H=4(p+1); sum = 192 per (b,ob)
    const int NBt[16] = {2, 3, 4, 6, 7, 8, 10, 11, 12, 14, 16, 17, 18, 20, 21, 23};

    int blk = blockIdx.x;                        // 768
    int orig = (blk & 7) * 96 + (blk >> 3);      // XCD-contiguous remap (bijective, 768%8==0)
    int bo = orig / 192;
    int b_ = bo >> 1, ob = bo & 1;
    int j = orig - bo * 192;
    int p = 0, base = 0;
    while (p < 15 && j >= base + NBt[p]) { base += NBt[p]; ++p; }
    int idx = j - base, n = NBt[p];
    int H = 4 * (p + 1);
    int u0 = idx * H / n, u1 = (idx + 1) * H / n;
    int nsteps = (u1 - u0) * 48;

    int tid = threadIdx.x, lane = tid & 63, wid = tid >> 6;
    int wr = wid >> 1, wc = wid & 1;
    int ln15 = lane & 15, lq = lane >> 4;
    int swz = lq ^ ((ln15 >> 1) & 3);

    auto stage = [&](int bufsel, int h, int c) {
        int tt = h >> 1, kk = h & 1;
        int d0 = 2 * p - tt;
        const ushort_t* Asrc = Tb2 + ((size_t)((d0 + 1) * NC + c) << 12) + kk * 32;
        const ushort_t* Bsrc = yt + ((size_t)((b_ * NC + c) * NO + ob * 128) << 11) + tt * 64 + kk * 32;
        ushort_t* L = sh + bufsel * 8192;
#pragma unroll
        for (int jj = 0; jj < 2; ++jj) {
            int flat = tid + jj * 256;
            int row = flat >> 2;
            int k8s = (flat & 3) ^ ((flat >> 3) & 3);
            glds16(L + flat * 8, Asrc + ((row >> 6) * NC << 12) + (row & 63) * 64 + k8s * 8);
        }
#pragma unroll
        for (int jj = 0; jj < 2; ++jj) {
            int flat = tid + jj * 256;
            int row = flat >> 2;
            int k8s = (flat & 3) ^ ((flat >> 3) & 3);
            glds16(L + 4096 + flat * 8, Bsrc + row * 2048 + k8s * 8);
        }
    };

    f32x4 acc[4][4];
    f32x4 z = {0.f, 0.f, 0.f, 0.f};
#pragma unroll
    for (int mi = 0; mi < 4; ++mi)
#pragma unroll
        for (int ni = 0; ni < 4; ++ni) acc[mi][ni] = z;

    int h = u0, c = 0;
    stage(0, h, c);
    int hn = h, cn = 1;
    if (cn == 48) { cn = 0; hn++; }
    __syncthreads();

    for (int s = 0; s < nsteps; ++s) {
        int cur = s & 1;
        if (s + 1 < nsteps) {
            stage(cur ^ 1, hn, cn);
            if (++cn == 48) { cn = 0; ++hn; }
        }
        const ushort_t* Ab = sh + cur * 8192;
        const ushort_t* Bb = Ab + 4096;
        bf16x8 af[4], bfr[4];
#pragma unroll
        for (int mi = 0; mi < 4; ++mi)
            af[mi] = *reinterpret_cast<const bf16x8*>(Ab + (wr * 64 + mi * 16 + ln15) * 32 + swz * 8);
#pragma unroll
        for (int ni = 0; ni < 4; ++ni)
            bfr[ni] = *reinterpret_cast<const bf16x8*>(Bb + (wc * 64 + ni * 16 + ln15) * 32 + swz * 8);
#pragma unroll
        for (int mi = 0; mi < 4; ++mi)
#pragma unroll
            for (int ni = 0; ni < 4; ++ni)
                acc[mi][ni] = __builtin_amdgcn_mfma_f32_16x16x32_bf16(af[mi], bfr[ni], acc[mi][ni], 0, 0, 0);
        __syncthreads();
    }

    float* outp = out + ((size_t)b_ * SL + p * 128) * NO + ob * 128;
#pragma unroll
    for (int mi = 0; mi < 4; ++mi)
#pragma unroll
        for (int ni = 0; ni < 4; ++ni) {
            int l = wr * 64 + mi * 16 + lq * 4;
            int o = wc * 64 + ni * 16 + ln15;
#pragma unroll
            for (int r = 0; r < 4; ++r) {
                atomicAdd(&outp[(l + r) * NO + o], acc[mi][ni][r]);
            }
        }
}

extern "C" void kernel_launch(void* const* d_in, const int* in_sizes, int n_in,
                              void* d_out, int out_size, void* d_ws, size_t ws_size,
                              hipStream_t stream) {
    const float* x   = (const float*)d_in[0];
    const float* phi = (const float*)d_in[1];
    const float* Mp  = (const float*)d_in[2];
    const float* Mm  = (const float*)d_in[3];
    float* out = (float*)d_out;

    if (ws_size < WS_NEED) return;

    char* ws = (char*)d_ws;
    ushort_t* T  = (ushort_t*)(ws + OFF_T);
    ushort_t* MT = (ushort_t*)(ws + OFF_MT);
    ushort_t* XB = (ushort_t*)(ws + OFF_XB);
    ushort_t* YT = (ushort_t*)(ws + OFF_YT);

    hipMemsetAsync(d_out, 0, (size_t)out_size * sizeof(float), stream);
    k_cvt_x<<<dim3(262144 / 256), dim3(256), 0, stream>>>(x, XB);
    k_mt<<<dim3(48, 4, 4), dim3(256), 0, stream>>>(Mp, Mm, MT);
    k_toep<<<dim3(33, 48), dim3(64), 0, stream>>>(phi, T);
    k_gemm1<<<dim3(96, 32), dim3(256), 0, stream>>>(XB, MT, YT);
    k_conv<<<dim3(768), dim3(256), 0, stream>>>(T, YT, out);
}

// Round 4
// 226.395 us; speedup vs baseline: 5.5662x; 1.0775x over previous
//
#include <hip/hip_runtime.h>
#include <hip/hip_bf16.h>

#define SL 2048
#define NK 24
#define NI 256
#define NO 256
#define NB 2
#define NC 48
#define TD 64

typedef __bf16 bf16x8 __attribute__((ext_vector_type(8)));
typedef float f32x4 __attribute__((ext_vector_type(4)));
typedef unsigned short u16x8 __attribute__((ext_vector_type(8)));
typedef unsigned short ushort_t;
typedef unsigned int u32;

// workspace layout (bytes)
// Toeplitz bank: 35 slots (slots 0..2 = zeros for d=-3..-1; slot s=d+3)
#define OFF_T   0ull
#define SZ_T    (35ull*48*64*64*2)        // 13,762,560
#define OFF_MT  (OFF_T + SZ_T)            // M_T [48][256][256] bf16 ([c][o][i])
#define SZ_MT   (48ull*256*256*2)
#define OFF_XB  (OFF_MT + SZ_MT)          // x bf16 [2][2048][256]
#define SZ_XB   (2ull*2048*256*2)
#define OFF_YT  (OFF_XB + SZ_XB)          // Y_T [2][48][256][2048] bf16 ([b][c][o][t])
#define SZ_YT   (2ull*48*256*2048*2)
#define WS_NEED (OFF_YT + SZ_YT)

__device__ __forceinline__ unsigned short f2bf(float f) {
    unsigned int u = __float_as_uint(f);
    unsigned int r = (u + 0x7FFFu + ((u >> 16) & 1u)) >> 16;
    return (unsigned short)r;
}

__device__ __forceinline__ void glds16(ushort_t* l, const ushort_t* g) {
    __builtin_amdgcn_global_load_lds((const __attribute__((address_space(1))) u32*)g,
                                     (__attribute__((address_space(3))) u32*)l, 16, 0, 0);
}

// ---- kernel 0a: x f32 -> bf16 -------------------------------------------
__global__ void k_cvt_x(const float* __restrict__ x, ushort_t* __restrict__ xb) {
    int i = blockIdx.x * blockDim.x + threadIdx.x;
    float4 v = reinterpret_cast<const float4*>(x)[i];
    ushort4 o;
    o.x = f2bf(v.x); o.y = f2bf(v.y); o.z = f2bf(v.z); o.w = f2bf(v.w);
    reinterpret_cast<ushort4*>(xb)[i] = o;
}

// ---- kernel 0b: M [k][i][o] f32 -> M_T [c][o][i] bf16 -------------------
__global__ void k_mt(const float* __restrict__ Mp, const float* __restrict__ Mm,
                     ushort_t* __restrict__ mt) {
    __shared__ float tile[64][65];
    int c = blockIdx.x, it = blockIdx.y, ot = blockIdx.z;
    int k = c >> 1;
    const float* M = (c & 1) ? Mm : Mp;
    int tid = threadIdx.x;
    int col = tid & 63, rq = tid >> 6;
    for (int rr = 0; rr < 64; rr += 4) {
        int i = rr + rq;
        tile[i][col] = M[((k * NI) + (it * 64 + i)) * NO + ot * 64 + col];
    }
    __syncthreads();
    for (int rr = 0; rr < 64; rr += 4) {
        int o = rr + rq;
        mt[((c * NO) + (ot * 64 + o)) * NI + it * 64 + col] = f2bf(tile[col][o]);
    }
}

// ---- kernel 1: Toeplitz bank, slot s=d+3: T[s][c][li][ti] = F[64d+li-ti, c]
__global__ void k_toep(const float* __restrict__ phi, ushort_t* __restrict__ T) {
    int d = (int)blockIdx.x - 3, c = blockIdx.y;
    int ti = threadIdx.x;
    int k = c >> 1, odd = c & 1;
    for (int li = 0; li < TD; ++li) {
        int s = d * TD + li - ti;
        float v = 0.f;
        if (s >= 0 && s < SL) {
            v = phi[s * NK + k];
            if (odd && (s & 1)) v = -v;
        }
        T[(((blockIdx.x) * NC + c) * TD + li) * TD + ti] = f2bf(v);
    }
}

// ---- kernel 2: Y_T[b][c][o][t] = sum_i x[b,t,i] * M_c[i,o] (round-3, known-good)
__global__ __launch_bounds__(256, 3) void k_gemm1(const ushort_t* __restrict__ XB,
                                                  const ushort_t* __restrict__ MT,
                                                  ushort_t* __restrict__ yt) {
    __shared__ ushort_t sh[17408];
    int nb_ = blockIdx.x;
    int rb  = blockIdx.y;
    int n0 = nb_ * 128;
    int tid = threadIdx.x, lane = tid & 63, wid = tid >> 6;
    int wr = wid >> 1, wc = wid & 1;
    int ln15 = lane & 15, lq = lane >> 4;
    int swz = lq ^ ((ln15 >> 1) & 3);

    const ushort_t* Arow = XB + (size_t)(rb * 128) * 256;
    const ushort_t* Brow = MT + (size_t)n0 * 256;

    auto stage = [&](int bufsel, int s) {
        ushort_t* L = sh + bufsel * 8192;
        int k0 = s * 32;
#pragma unroll
        for (int jj = 0; jj < 2; ++jj) {
            int flat = tid + jj * 256;
            int row = flat >> 2;
            int k8s = (flat & 3) ^ ((flat >> 3) & 3);
            glds16(L + flat * 8, Arow + row * 256 + k0 + k8s * 8);
        }
#pragma unroll
        for (int jj = 0; jj < 2; ++jj) {
            int flat = tid + jj * 256;
            int row = flat >> 2;
            int k8s = (flat & 3) ^ ((flat >> 3) & 3);
            glds16(L + 4096 + flat * 8, Brow + row * 256 + k0 + k8s * 8);
        }
    };

    f32x4 acc[4][4];
    f32x4 z = {0.f, 0.f, 0.f, 0.f};
#pragma unroll
    for (int mi = 0; mi < 4; ++mi)
#pragma unroll
        for (int ni = 0; ni < 4; ++ni) acc[mi][ni] = z;

    stage(0, 0);
    __syncthreads();
    for (int s = 0; s < 8; ++s) {
        int cur = s & 1;
        if (s < 7) stage(cur ^ 1, s + 1);
        const ushort_t* Ab = sh + cur * 8192;
        const ushort_t* Bb = Ab + 4096;
        bf16x8 af[4], bfr[4];
#pragma unroll
        for (int mi = 0; mi < 4; ++mi)
            af[mi] = *reinterpret_cast<const bf16x8*>(Ab + (wr * 64 + mi * 16 + ln15) * 32 + swz * 8);
#pragma unroll
        for (int ni = 0; ni < 4; ++ni)
            bfr[ni] = *reinterpret_cast<const bf16x8*>(Bb + (wc * 64 + ni * 16 + ln15) * 32 + swz * 8);
#pragma unroll
        for (int mi = 0; mi < 4; ++mi)
#pragma unroll
            for (int ni = 0; ni < 4; ++ni)
                acc[mi][ni] = __builtin_amdgcn_mfma_f32_16x16x32_bf16(af[mi], bfr[ni], acc[mi][ni], 0, 0, 0);
        __syncthreads();
    }

    ushort_t* OT = sh;  // [128 n][136]
#pragma unroll
    for (int mi = 0; mi < 4; ++mi)
#pragma unroll
        for (int ni = 0; ni < 4; ++ni) {
            int t_loc = wr * 64 + mi * 16 + lq * 4;
            int n_loc = wc * 64 + ni * 16 + ln15;
            ushort4 pk;
            pk.x = f2bf(acc[mi][ni][0]);
            pk.y = f2bf(acc[mi][ni][1]);
            pk.z = f2bf(acc[mi][ni][2]);
            pk.w = f2bf(acc[mi][ni][3]);
            *reinterpret_cast<ushort4*>(OT + n_loc * 136 + t_loc) = pk;
        }
    __syncthreads();
    int b = rb >> 4, t0 = (rb & 15) * 128;
#pragma unroll
    for (int jj = 0; jj < 8; ++jj) {
        int flat = tid + jj * 256;
        int n_loc = flat >> 4, te = (flat & 15) * 8;
        int nn = n0 + n_loc;
        int c = nn >> 8, o = nn & 255;
        *reinterpret_cast<u16x8*>(yt + ((size_t)(b * NC + c) * NO + o) * SL + t0 + te) =
            *reinterpret_cast<const u16x8*>(OT + n_loc * 136 + te);
    }
}

// ---- kernel 3: conv as 256x256-tile 8-phase split-K block-Toeplitz GEMM --
// 8 waves (2M x 4N), wave tile 128x64, K-tile = 64 (one (tt,c) unit).
// LDS: A[par][256][64] + B[par][256][64] bf16 = 128 KiB, region-staged:
//   A-region qm = rows {(row>>6)&1 == qm}; B-region qn = rows {(row>>5)&1 == qn}
// Phase q=(qm,qn)=(q>>1,q&1); issues: q0:B1(s+1) q1:A1(s+1) q2:A0(s+2) q3:B0(s+2)
// vmcnt(4) once per K-tile boundary (vmcnt(0) only at the last two boundaries).
#define LOADFRAGS(QM, QN) do {                                                      \
    int arb = wr * 128 + (QM) * 64;                                                 \
    _Pragma("unroll") for (int m = 0; m < 4; ++m) {                                 \
        int row = arb + m * 16 + ln15;                                              \
        _Pragma("unroll") for (int kk = 0; kk < 2; ++kk)                            \
            af[m][kk] = *(const bf16x8*)(Ab + row * 64 + ((kk * 4 + lq) ^ (row & 7)) * 8); \
    }                                                                               \
    int brb = wc * 64 + (QN) * 32;                                                  \
    _Pragma("unroll") for (int n2 = 0; n2 < 2; ++n2) {                              \
        int row = brb + n2 * 16 + ln15;                                             \
        _Pragma("unroll") for (int kk = 0; kk < 2; ++kk)                            \
            bv[n2][kk] = *(const bf16x8*)(Bb + row * 64 + ((kk * 4 + lq) ^ (row & 7)) * 8); \
    }                                                                               \
} while (0)

#define MFMAS(QM, QN) do {                                                          \
    _Pragma("unroll") for (int m = 0; m < 4; ++m)                                   \
    _Pragma("unroll") for (int n2 = 0; n2 < 2; ++n2) {                              \
        acc[(QM)*4+m][(QN)*2+n2] = __builtin_amdgcn_mfma_f32_16x16x32_bf16(         \
            af[m][0], bv[n2][0], acc[(QM)*4+m][(QN)*2+n2], 0, 0, 0);                \
        acc[(QM)*4+m][(QN)*2+n2] = __builtin_amdgcn_mfma_f32_16x16x32_bf16(         \
            af[m][1], bv[n2][1], acc[(QM)*4+m][(QN)*2+n2], 0, 0, 0);                \
    }                                                                               \
} while (0)

#define PHASE_TAIL()                                                                \
    __builtin_amdgcn_s_barrier();                                                   \
    asm volatile("s_waitcnt lgkmcnt(0)" ::: "memory");                              \
    __builtin_amdgcn_sched_barrier(0);                                              \
    __builtin_amdgcn_s_setprio(1)

__global__ __launch_bounds__(512, 2) void k_conv8(const ushort_t* __restrict__ Tb,
                                                  const ushort_t* __restrict__ yt,
                                                  float* __restrict__ out) {
    __shared__ ushort_t sh[65536];   // A par0|par1 @0,16384 ; B par0|par1 @32768,49152

    int blk = blockIdx.x;                       // 256
    int orig = (blk & 7) * 32 + (blk >> 3);     // XCD-chunked bijective (256%8==0)
    const int NBt[8] = {4, 7, 11, 14, 18, 21, 25, 28};   // sum = 128 per batch
    int b_ = orig >> 7;
    int j = orig & 127;
    int pp = 0, base = 0;
    while (pp < 7 && j >= base + NBt[pp]) { base += NBt[pp]; ++pp; }
    int idx = j - base, n = NBt[pp];
    int U = 192 * (pp + 1);                     // K-tiles in this group
    int u0 = idx * U / n, u1 = (idx + 1) * U / n;

    int tid = threadIdx.x, lane = tid & 63, wid = tid >> 6;
    int wr = wid >> 2, wc = wid & 3;            // 2M x 4N waves
    int ln15 = lane & 15, lq = lane >> 4;

    const ushort_t* YTb = yt + ((size_t)(b_ * NC * NO) << 11);

    auto stageA = [&](int qm, int u) {
        int tt = u / 48, c = u - tt * 48;
        ushort_t* L = sh + (u & 1) * 16384;
#pragma unroll
        for (int jj = 0; jj < 2; ++jj) {
            int row = jj * 128 + qm * 64 + (tid >> 3);
            int sl = tid & 7;
            int s_idx = 4 * pp + (row >> 6) - tt + 3;
            const ushort_t* src = Tb + (((size_t)(s_idx * NC + c)) << 12)
                                + (row & 63) * 64 + ((sl ^ (row & 7)) * 8);
            glds16(L + row * 64 + sl * 8, src);
        }
    };
    auto stageB = [&](int qn, int u) {
        int tt = u / 48, c = u - tt * 48;
        ushort_t* L = sh + 32768 + (u & 1) * 16384;
#pragma unroll
        for (int jj = 0; jj < 2; ++jj) {
            int rr = tid + jj * 512;
            int ro = rr >> 3, sl = rr & 7;
            int row = (ro >> 5) * 64 + qn * 32 + (ro & 31);
            const ushort_t* src = YTb + (((size_t)(c * NO + row)) << 11)
                                + tt * 64 + ((sl ^ (row & 7)) * 8);
            glds16(L + row * 64 + sl * 8, src);
        }
    };

    f32x4 acc[8][4];
    f32x4 z = {0.f, 0.f, 0.f, 0.f};
#pragma unroll
    for (int mi = 0; mi < 8; ++mi)
#pragma unroll
        for (int ni = 0; ni < 4; ++ni) acc[mi][ni] = z;

    // prologue: K0 fully + K1's A0,B0 (order matches steady-state vmcnt counting)
    stageA(0, u0); stageB(0, u0); stageB(1, u0); stageA(1, u0);
    stageA(0, u0 + 1); stageB(0, u0 + 1);
    asm volatile("s_waitcnt vmcnt(4)" ::: "memory");
    __builtin_amdgcn_s_barrier();

    for (int s = u0; s < u1; ++s) {
        const ushort_t* Ab = sh + (s & 1) * 16384;
        const ushort_t* Bb = sh + 32768 + (s & 1) * 16384;
        bf16x8 af[4][2], bv[2][2];

        // phase q0: (0,0) ; issue B1(s+1)
        LOADFRAGS(0, 0);
        if (s + 1 < u1) stageB(1, s + 1);
        PHASE_TAIL();
        MFMAS(0, 0);
        __builtin_amdgcn_s_setprio(0);
        __builtin_amdgcn_s_barrier();

        // phase q1: (0,1) ; issue A1(s+1)
        LOADFRAGS(0, 1);
        if (s + 1 < u1) stageA(1, s + 1);
        PHASE_TAIL();
        MFMAS(0, 1);
        __builtin_amdgcn_s_setprio(0);
        __builtin_amdgcn_s_barrier();

        // phase q2: (1,0) ; issue A0(s+2)
        LOADFRAGS(1, 0);
        if (s + 2 < u1) stageA(0, s + 2);
        PHASE_TAIL();
        MFMAS(1, 0);
        __builtin_amdgcn_s_setprio(0);
        __builtin_amdgcn_s_barrier();

        // phase q3: (1,1) ; issue B0(s+2) ; counted vmcnt at K-tile boundary
        LOADFRAGS(1, 1);
        if (s + 2 < u1) stageB(0, s + 2);
        PHASE_TAIL();
        MFMAS(1, 1);
        __builtin_amdgcn_s_setprio(0);
        if (s + 2 < u1) asm volatile("s_waitcnt vmcnt(4)" ::: "memory");
        else            asm volatile("s_waitcnt vmcnt(0)" ::: "memory");
        __builtin_amdgcn_s_barrier();
    }

    float* outp = out + (((size_t)b_ * SL) + (size_t)pp * 256) * NO;
#pragma unroll
    for (int mi = 0; mi < 8; ++mi)
#pragma unroll
        for (int ni = 0; ni < 4; ++ni) {
            int l = wr * 128 + mi * 16 + lq * 4;
            int o = wc * 64 + ni * 16 + ln15;
#pragma unroll
            for (int r = 0; r < 4; ++r)
                atomicAdd(&outp[(size_t)(l + r) * NO + o], acc[mi][ni][r]);
        }
}

extern "C" void kernel_launch(void* const* d_in, const int* in_sizes, int n_in,
                              void* d_out, int out_size, void* d_ws, size_t ws_size,
                              hipStream_t stream) {
    const float* x   = (const float*)d_in[0];
    const float* phi = (const float*)d_in[1];
    const float* Mp  = (const float*)d_in[2];
    const float* Mm  = (const float*)d_in[3];
    float* out = (float*)d_out;

    if (ws_size < WS_NEED) return;

    char* ws = (char*)d_ws;
    ushort_t* T  = (ushort_t*)(ws + OFF_T);
    ushort_t* MT = (ushort_t*)(ws + OFF_MT);
    ushort_t* XB = (ushort_t*)(ws + OFF_XB);
    ushort_t* YT = (ushort_t*)(ws + OFF_YT);

    hipMemsetAsync(d_out, 0, (size_t)out_size * sizeof(float), stream);
    k_cvt_x<<<dim3(262144 / 256), dim3(256), 0, stream>>>(x, XB);
    k_mt<<<dim3(48, 4, 4), dim3(256), 0, stream>>>(Mp, Mm, MT);
    k_toep<<<dim3(35, 48), dim3(64), 0, stream>>>(phi, T);
    k_gemm1<<<dim3(96, 32), dim3(256), 0, stream>>>(XB, MT, YT);
    k_conv8<<<dim3(256), dim3(512), 0, stream>>>(T, YT, out);
}